// Round 7
// baseline (264.088 us; speedup 1.0000x reference)
//
#include <hip/hip_runtime.h>
#include <hip/hip_bf16.h>
#include <hip/hip_cooperative_groups.h>
#include <stdint.h>

namespace cg = cooperative_groups;

#define B_    4
#define S_    4096
#define F_    1024
#define A_    512
#define N3_   1536
#define M_    16384

#define BM    256
#define BK    64
#define NT    (F_ / BK)   // 16 K-tiles
#define LDP   266         // Xt col-major stride (elems)

typedef __attribute__((ext_vector_type(8)))  __bf16 bf16x8;
typedef __attribute__((ext_vector_type(4)))  float  f32x4;
typedef __attribute__((ext_vector_type(16))) float  f32x16;

#define MFMA32(a, b, c) __builtin_amdgcn_mfma_f32_32x32x16_bf16((a), (b), (c), 0, 0, 0)

// ---------- helpers ----------
__device__ __forceinline__ float bflo(unsigned int u) {
  union { unsigned int i; float f; } v; v.i = u << 16; return v.f;
}
__device__ __forceinline__ float bfhi(unsigned int u) {
  union { unsigned int i; float f; } v; v.i = u & 0xffff0000u; return v.f;
}
__device__ __forceinline__ float bf1(unsigned short u) {
  union { unsigned int i; float f; } v; v.i = ((unsigned int)u) << 16; return v.f;
}
__device__ __forceinline__ unsigned short bfc(float f) {
  return __builtin_bit_cast(unsigned short, __float2bfloat16(f));
}
__device__ __forceinline__ ushort4 cvt_bf4(float4 v) {
  ushort4 o;
  o.x = bfc(v.x); o.y = bfc(v.y); o.z = bfc(v.z); o.w = bfc(v.w);
  return o;
}

typedef __attribute__((address_space(3))) unsigned int lds_uint;
typedef const __attribute__((address_space(1))) unsigned int glob_uint;
__device__ __forceinline__ void lds_load16(const void* g, void* l) {
  __builtin_amdgcn_global_load_lds((glob_uint*)g, (lds_uint*)l, 16, 0, 0);
}

// ---------- K1: convert inp -> bf16 (+ column sums for mean), W[1536:3072] -> bf16 ----------
__global__ __launch_bounds__(256) void convert_mean_kernel(
    const float* __restrict__ inp, const float* __restrict__ W,
    unsigned short* __restrict__ inp_bf, unsigned short* __restrict__ w_bf,
    float* __restrict__ mu) {
  int blk = blockIdx.x;   // 512
  int t   = threadIdx.x;  // 256
  int r0  = blk * 32;
  int b   = r0 >> 12;
  float acc0 = 0.f, acc1 = 0.f, acc2 = 0.f, acc3 = 0.f;
  for (int r = 0; r < 32; r++) {
    size_t row = (size_t)(r0 + r);
    float4 v = ((const float4*)(inp + row * F_))[t];
    acc0 += v.x; acc1 += v.y; acc2 += v.z; acc3 += v.w;
    ((ushort4*)(inp_bf + row * F_))[t] = cvt_bf4(v);
  }
  atomicAdd(&mu[b * F_ + t * 4 + 0], acc0);
  atomicAdd(&mu[b * F_ + t * 4 + 1], acc1);
  atomicAdd(&mu[b * F_ + t * 4 + 2], acc2);
  atomicAdd(&mu[b * F_ + t * 4 + 3], acc3);

  const float* Wc = W + (size_t)N3_ * F_;
  const int n4 = (N3_ * F_) / 4;
  for (int i = blk * 256 + t; i < n4; i += 512 * 256) {
    ((ushort4*)w_bf)[i] = cvt_bf4(((const float4*)Wc)[i]);
  }
}

// ---------- K2: cooperative chain: agg -> v+cvec -> scores -> softmax -> u -> ctx ----------
__global__ __launch_bounds__(512) void chain_kernel(
    const float* __restrict__ mu, const float* __restrict__ W,
    const float* __restrict__ bias, const unsigned short* __restrict__ inp_bf,
    float* __restrict__ agg, float* __restrict__ v, float* __restrict__ cvec,
    float* __restrict__ scores, float* __restrict__ u, float* __restrict__ ctx) {
  cg::grid_group grid = cg::this_grid();
  __shared__ float red[512];
  int blk = blockIdx.x;   // 256
  int t   = threadIdx.x;  // 512
  int lane = t & 63, wv = t >> 6;  // 8 waves

  // ---- stage A: agg[b,a] (2048 wave-dots, 1 per wave)
  {
    int gw = blk * 8 + wv;  // 0..2047
    int b = gw >> 9, a = gw & 511;
    const float4* wr = (const float4*)(W + (size_t)a * F_);
    const float4* mr = (const float4*)(mu + b * F_);
    float s = 0.f;
#pragma unroll
    for (int k = 0; k < 4; k++) {
      float4 wvv = wr[lane + 64 * k], mv = mr[lane + 64 * k];
      s += wvv.x * mv.x + wvv.y * mv.y + wvv.z * mv.z + wvv.w * mv.w;
    }
    for (int off = 32; off; off >>= 1) s += __shfl_down(s, off);
    if (lane == 0) agg[b * A_ + a] = s * (1.f / S_) + bias[a];
  }
  grid.sync();

  // ---- stage B: v[b,f] (atomic partials) + cvec[b]
  {
    int fc = blk & 1, ac = blk >> 1;        // 2 f-halves x 128 a-chunks of 4
    int f = fc * 512 + t;
    const float* Wk = W + (size_t)A_ * F_;
    float s0 = 0.f, s1 = 0.f, s2 = 0.f, s3 = 0.f;
    int a0 = ac * 4;
    for (int a = a0; a < a0 + 4; a++) {
      float wvv = Wk[(size_t)a * F_ + f];
      s0 += agg[a] * wvv;
      s1 += agg[A_ + a] * wvv;
      s2 += agg[2 * A_ + a] * wvv;
      s3 += agg[3 * A_ + a] * wvv;
    }
    atomicAdd(&v[f], s0);
    atomicAdd(&v[F_ + f], s1);
    atomicAdd(&v[2 * F_ + f], s2);
    atomicAdd(&v[3 * F_ + f], s3);
    if (blk == 0 && wv < 4) {
      float c = 0.f;
#pragma unroll
      for (int i = 0; i < 8; i++) c += agg[wv * A_ + lane + 64 * i] * bias[A_ + lane + 64 * i];
      for (int off = 32; off; off >>= 1) c += __shfl_down(c, off);
      if (lane == 0) cvec[wv] = c;
    }
  }
  grid.sync();

  // ---- stage C: scores (8 rows per wave)
  {
#pragma unroll
    for (int d = 0; d < 8; d++) {
      int row = blk * 64 + wv * 8 + d;
      int b = row >> 12;
      const uint4* ip = (const uint4*)(inp_bf + (size_t)row * F_);
      const float4* vp = (const float4*)(v + b * F_);
      float s = 0.f;
#pragma unroll
      for (int k = 0; k < 2; k++) {
        uint4 x = ip[lane + 64 * k];
        float4 va = vp[(lane + 64 * k) * 2];
        float4 vb = vp[(lane + 64 * k) * 2 + 1];
        s += bflo(x.x) * va.x + bfhi(x.x) * va.y + bflo(x.y) * va.z + bfhi(x.y) * va.w +
             bflo(x.z) * vb.x + bfhi(x.z) * vb.y + bflo(x.w) * vb.z + bfhi(x.w) * vb.w;
      }
      for (int off = 32; off; off >>= 1) s += __shfl_down(s, off);
      if (lane == 0) scores[row] = s + cvec[b];
    }
  }
  grid.sync();

  // ---- stage D: softmax (blocks 0..3 only)
  if (blk < 4) {
    float* p = scores + blk * S_;
    float vals[8];
    float m = -1e30f;
#pragma unroll
    for (int i = 0; i < 8; i++) { vals[i] = p[t + i * 512]; m = fmaxf(m, vals[i]); }
    red[t] = m; __syncthreads();
    for (int o = 256; o; o >>= 1) { if (t < o) red[t] = fmaxf(red[t], red[t + o]); __syncthreads(); }
    m = red[0]; __syncthreads();
    float sum = 0.f;
#pragma unroll
    for (int i = 0; i < 8; i++) { vals[i] = __expf(vals[i] - m); sum += vals[i]; }
    red[t] = sum; __syncthreads();
    for (int o = 256; o; o >>= 1) { if (t < o) red[t] += red[t + o]; __syncthreads(); }
    float inv = 1.f / red[0];
#pragma unroll
    for (int i = 0; i < 8; i++) p[t + i * 512] = vals[i] * inv;
  }
  grid.sync();

  // ---- stage E: u[b,f] (atomic partials over 64-row s-chunks)
  {
    int b = blk & 3, sc = blk >> 2;   // 64 s-chunks of 64
    int s0 = sc * 64;
    int f2 = t * 2;
    const float* wp = scores + b * S_ + s0;
    const unsigned short* ip = inp_bf + ((size_t)(b * S_ + s0)) * F_ + f2;
    float a0 = 0.f, a1 = 0.f;
    for (int s = 0; s < 64; s++) {
      unsigned int xv = *(const unsigned int*)&ip[(size_t)s * F_];
      float ws = wp[s];
      a0 += ws * bflo(xv);
      a1 += ws * bfhi(xv);
    }
    atomicAdd(&u[b * F_ + f2], a0);
    atomicAdd(&u[b * F_ + f2 + 1], a1);
  }
  grid.sync();

  // ---- stage F: ctx[b,a] (2048 wave-dots)
  {
    int gw = blk * 8 + wv;
    int b = gw >> 9, a = gw & 511;
    const float4* wr = (const float4*)(W + (size_t)(2 * A_ + a) * F_);
    const float4* ur = (const float4*)(u + b * F_);
    float s = 0.f;
#pragma unroll
    for (int k = 0; k < 4; k++) {
      float4 wvv = wr[lane + 64 * k], uv = ur[lane + 64 * k];
      s += wvv.x * uv.x + wvv.y * uv.y + wvv.z * uv.z + wvv.w * uv.w;
    }
    for (int off = 32; off; off >>= 1) s += __shfl_down(s, off);
    if (lane == 0) ctx[b * A_ + a] = s + bias[2 * A_ + a];
  }
}

// ---------- K3: fused GEMM (32x32x16 MFMA, 2-barrier counted-vmcnt loop) + final ----------
__global__ __launch_bounds__(512, 2) void gemm_fused(
    const __hip_bfloat16* __restrict__ Abf,
    const __hip_bfloat16* __restrict__ Wbf,
    const float* __restrict__ biasP,   // bias + 1536
    const float* __restrict__ ctx,
    float* __restrict__ out,
    unsigned short* __restrict__ sideLoc,
    float* __restrict__ sideGO) {
  extern __shared__ unsigned short smem[];
  unsigned short* ldsA = smem;            // 2 x 16384 elems
  unsigned short* ldsB = smem + 32768;    // 2 x 12288 elems
  unsigned short* Xt   = smem;            // epilogue alias: [192 cols][266 rows]
  float* segred = (float*)((char*)smem + 192 * LDP * 2);  // 4 x 64 f32

  int bid = blockIdx.x;
  int swz = (bid & 7) * 64 + (bid >> 3);  // 512 blocks, 8 XCDs, bijective
  int mb = swz >> 3;   // 0..63
  int nb = swz & 7;    // 0..7

  int tid  = threadIdx.x;
  int lane = tid & 63;
  int wv   = tid >> 6;       // 0..7
  int wm   = wv >> 1;        // 0..3 : 64-row slice
  int wn   = wv & 1;         // 0..1 : 96-col slice
  int l31  = lane & 31, half = lane >> 5, r7 = l31 & 7;

  // swizzled in-row element offsets for the 4 k-slices of 16 (slot = ks*2+half, XOR row&7)
  int eo[4];
#pragma unroll
  for (int ks = 0; ks < 4; ks++) eo[ks] = ((ks * 2 + half) ^ r7) * 8;

  const __hip_bfloat16* Ab = Abf + (size_t)mb * BM * F_;

  int srow = tid >> 3;                       // 0..63
  int sel  = ((tid & 7) ^ (srow & 7)) * 8;
  int ldst = wv * 512;

  const f32x16 zero16 = {0.f,0.f,0.f,0.f,0.f,0.f,0.f,0.f,0.f,0.f,0.f,0.f,0.f,0.f,0.f,0.f};
  f32x16 acc[2][3];
#pragma unroll
  for (int i = 0; i < 2; i++)
#pragma unroll
    for (int j = 0; j < 3; j++) acc[i][j] = zero16;

  int aRowBase = (wm * 64 + l31) * 64;   // + fi*32 rows -> +fi*2048 elems
  int bRowBase = (wn * 96 + l31) * 64;   // + fj*32 rows -> +fj*2048 elems

#define STG_A(kt_, buf_, r_)                                                              \
  lds_load16(Ab + (size_t)((r_) * 64 + srow) * F_ + (kt_) * BK + sel,                     \
             ldsA + (buf_) * 16384 + (r_) * 4096 + ldst)
#define STG_B(kt_, buf_, q_)                                                              \
  lds_load16(Wbf + (size_t)((q_) * 512 + nb * 64 + srow) * F_ + (kt_) * BK + sel,         \
             ldsB + (buf_) * 12288 + (q_) * 4096 + ldst)

  // prologue: stage tile 0 (7 loads)
  STG_A(0, 0, 0); STG_A(0, 0, 1); STG_A(0, 0, 2); STG_A(0, 0, 3);
  STG_B(0, 0, 0); STG_B(0, 0, 1); STG_B(0, 0, 2);

  for (int kt = 0; kt < NT; ++kt) {
    int c = kt & 1, nx = c ^ 1;
    bool pf = (kt + 1 < NT);
    const unsigned short* la = ldsA + c * 16384;
    const unsigned short* lb = ldsB + c * 12288;

    __builtin_amdgcn_s_barrier();            // all waves done reading buf nx (prev tile)
    if (pf) {
      STG_A(kt + 1, nx, 0); STG_A(kt + 1, nx, 1); STG_A(kt + 1, nx, 2); STG_A(kt + 1, nx, 3);
      asm volatile("s_waitcnt vmcnt(4)" ::: "memory");   // tile-kt's 7 loads landed
    } else {
      asm volatile("s_waitcnt vmcnt(0)" ::: "memory");
    }
    __builtin_amdgcn_s_barrier();            // buf c visible to all waves

    bf16x8 a0[2][2], b0[3][2];
    // ---- ks-slices 0,1 : reads + 12 MFMA (compiler fine-schedules lgkm waits)
#pragma unroll
    for (int fi = 0; fi < 2; fi++)
#pragma unroll
      for (int ks = 0; ks < 2; ks++)
        a0[fi][ks] = *(const bf16x8*)&la[aRowBase + fi * 2048 + eo[ks]];
#pragma unroll
    for (int fj = 0; fj < 3; fj++)
#pragma unroll
      for (int ks = 0; ks < 2; ks++)
        b0[fj][ks] = *(const bf16x8*)&lb[bRowBase + fj * 2048 + eo[ks]];
    __builtin_amdgcn_s_setprio(1);
#pragma unroll
    for (int ks = 0; ks < 2; ks++)
#pragma unroll
      for (int fi = 0; fi < 2; fi++)
#pragma unroll
        for (int fj = 0; fj < 3; fj++)
          acc[fi][fj] = MFMA32(a0[fi][ks], b0[fj][ks], acc[fi][fj]);
    __builtin_amdgcn_s_setprio(0);

    if (pf) { STG_B(kt + 1, nx, 0); STG_B(kt + 1, nx, 1); STG_B(kt + 1, nx, 2); }

    // ---- ks-slices 2,3
#pragma unroll
    for (int fi = 0; fi < 2; fi++)
#pragma unroll
      for (int ks = 0; ks < 2; ks++)
        a0[fi][ks] = *(const bf16x8*)&la[aRowBase + fi * 2048 + eo[2 + ks]];
#pragma unroll
    for (int fj = 0; fj < 3; fj++)
#pragma unroll
      for (int ks = 0; ks < 2; ks++)
        b0[fj][ks] = *(const bf16x8*)&lb[bRowBase + fj * 2048 + eo[2 + ks]];
    __builtin_amdgcn_s_setprio(1);
#pragma unroll
    for (int ks = 0; ks < 2; ks++)
#pragma unroll
      for (int fi = 0; fi < 2; fi++)
#pragma unroll
        for (int fj = 0; fj < 3; fj++)
          acc[fi][fj] = MFMA32(a0[fi][ks], b0[fj][ks], acc[fi][fj]);
    __builtin_amdgcn_s_setprio(0);
  }
#undef STG_A
#undef STG_B

  __syncthreads();   // all waves done with staging LDS before Xt overwrite

  // ---------------- epilogue ----------------
  // acc (+bias) -> Xt col-major bf16. C/D: col=lane&31, row=(reg&3)+8*(reg>>2)+4*half.
  float bias_r[3];
#pragma unroll
  for (int fj = 0; fj < 3; fj++) {
    int cl = wn * 96 + fj * 32 + l31;
    bias_r[fj] = biasP[(cl >> 6) * 512 + nb * 64 + (cl & 63)];
  }
#pragma unroll
  for (int fi = 0; fi < 2; fi++) {
#pragma unroll
    for (int fj = 0; fj < 3; fj++) {
      int cl = wn * 96 + fj * 32 + l31;
      int rbase = wm * 64 + fi * 32 + half * 4;
#pragma unroll
      for (int q = 0; q < 4; q++) {
        int r = rbase + q * 8;
        float v0 = acc[fi][fj][4 * q + 0] + bias_r[fj];
        float v1 = acc[fi][fj][4 * q + 1] + bias_r[fj];
        float v2 = acc[fi][fj][4 * q + 2] + bias_r[fj];
        float v3 = acc[fi][fj][4 * q + 3] + bias_r[fj];
        unsigned int u01 = (unsigned int)bfc(v0) | ((unsigned int)bfc(v1) << 16);
        unsigned int u23 = (unsigned int)bfc(v2) | ((unsigned int)bfc(v3) << 16);
        *(unsigned int*)&Xt[cl * LDP + r]     = u01;
        *(unsigned int*)&Xt[cl * LDP + r + 2] = u23;
      }
    }
  }
  __syncthreads();

  // segment maxes: seg strip = Xt cols 0..63
  if (tid < 256) {
    int seg = tid >> 6, c = tid & 63;
    int base = c * LDP + seg * 64;
    float m = -1e30f;
#pragma unroll
    for (int k = 0; k < 32; k++) {
      unsigned int uu = *(const unsigned int*)&Xt[base + 2 * k];
      m = fmaxf(m, fmaxf(bflo(uu), bfhi(uu)));
    }
    segred[seg * 64 + c] = m;
  }
  __syncthreads();

  // final combine: wave wv owns rows wv*32..+31, lane = col c (0..63)
  {
    int c  = lane;
    int r0 = wv * 32;
    int b  = mb >> 4;
    int gcol = nb * 64 + c;
    float g = ctx[b * 512 + gcol] + segred[(r0 >> 6) * 64 + c];
    int lbase = (64 + c) * LDP;
    int obase = (128 + c) * LDP;
    float lw0 = bf1(Xt[lbase + max(r0 - 2, 0)]);
    float lw1 = bf1(Xt[lbase + max(r0 - 1, 0)]);
    float lw2 = bf1(Xt[lbase + r0]);
    float lw3 = bf1(Xt[lbase + r0 + 1]);
    size_t obase_g = ((size_t)(mb * 256 + r0)) * 512 + gcol;
#pragma unroll
    for (int j = 0; j < 32; j++) {
      int rn = min(r0 + j + 2, 255);
      float lw4 = bf1(Xt[lbase + rn]);
      float lm = fmaxf(fmaxf(fmaxf(lw0, lw1), fmaxf(lw2, lw3)), lw4);
      float o = bf1(Xt[obase + r0 + j]);
      out[obase_g + (size_t)j * 512] = g * o + lm;
      lw0 = lw1; lw1 = lw2; lw2 = lw3; lw3 = lw4;
    }
  }

  // side buffers for tile-boundary loc-window fixup (rows 0,1,254,255)
  if (tid < 256) {
    int rsel = tid >> 6, c = tid & 63;
    int r = (rsel < 2) ? rsel : (252 + rsel);   // 0,1,254,255
    int b = mb >> 4;
    float g = ctx[b * 512 + nb * 64 + c] + segred[(r >> 6) * 64 + c];
    float o = bf1(Xt[(128 + c) * LDP + r]);
    int gr = mb * 4 + rsel;
    sideLoc[gr * 512 + nb * 64 + c] = Xt[(64 + c) * LDP + r];
    sideGO[gr * 512 + nb * 64 + c]  = g * o;
  }
}

// ---------- K4: fixup for loc windows crossing 256-row tile boundaries ----------
__global__ void fixup_kernel(const unsigned short* __restrict__ sideLoc,
                             const float* __restrict__ sideGO,
                             float* __restrict__ out) {
  int rb = blockIdx.x;      // 0..63
  int tb = rb & 15;         // tile index within b
  int t = threadIdx.x;      // 256
  int rsel = t >> 6, cq = t & 63;
#pragma unroll
  for (int k = 0; k < 8; k++) {
    int c = cq * 8 + k;
    float miss;
    int rl;
    if (rsel == 0) {
      if (tb == 0) continue;
      miss = fmaxf(bf1(sideLoc[((rb - 1) * 4 + 2) * 512 + c]),
                   bf1(sideLoc[((rb - 1) * 4 + 3) * 512 + c]));
      rl = 0;
    } else if (rsel == 1) {
      if (tb == 0) continue;
      miss = bf1(sideLoc[((rb - 1) * 4 + 3) * 512 + c]);
      rl = 1;
    } else if (rsel == 2) {
      if (tb == 15) continue;
      miss = bf1(sideLoc[((rb + 1) * 4 + 0) * 512 + c]);
      rl = 254;
    } else {
      if (tb == 15) continue;
      miss = fmaxf(bf1(sideLoc[((rb + 1) * 4 + 0) * 512 + c]),
                   bf1(sideLoc[((rb + 1) * 4 + 1) * 512 + c]));
      rl = 255;
    }
    size_t oi = ((size_t)rb * 256 + rl) * 512 + c;
    float cand = sideGO[(rb * 4 + rsel) * 512 + c] + miss;
    out[oi] = fmaxf(out[oi], cand);
  }
}

// ---------- launch ----------
extern "C" void kernel_launch(void* const* d_in, const int* in_sizes, int n_in,
                              void* d_out, int out_size, void* d_ws, size_t ws_size,
                              hipStream_t stream) {
  const float* inp  = (const float*)d_in[0];
  const float* W    = (const float*)d_in[1];
  const float* bias = (const float*)d_in[2];
  float* out = (float*)d_out;
  char* ws = (char*)d_ws;

  const size_t INP_OFF  = 0;                   // bf16 inp: 33,554,432
  const size_t W_OFF    = 33554432;            // bf16 W[1536:3072]: 3,145,728
  const size_t MU_OFF   = 36700160;            // f32 mu: 16,384
  const size_t U_OFF    = MU_OFF + 16384;
  const size_t V_OFF    = U_OFF + 16384;
  const size_t CV_OFF   = V_OFF + 16384;       // 256
  const size_t AGG_OFF  = CV_OFF + 256;        // 8,192
  const size_t CTX_OFF  = AGG_OFF + 8192;      // 8,192
  const size_t SC_OFF   = CTX_OFF + 8192;      // 65,536
  const size_t SL_OFF   = SC_OFF + 65536;      // sideLoc bf16: 262,144
  const size_t SG_OFF   = SL_OFF + 262144;     // sideGO f32: 524,288

  const unsigned short* inp_bf_c = (const unsigned short*)(ws + INP_OFF);
  unsigned short* inp_bf = (unsigned short*)(ws + INP_OFF);
  unsigned short* w_bf   = (unsigned short*)(ws + W_OFF);
  float* mu     = (float*)(ws + MU_OFF);
  float* u      = (float*)(ws + U_OFF);
  float* v      = (float*)(ws + V_OFF);
  float* cvec   = (float*)(ws + CV_OFF);
  float* agg    = (float*)(ws + AGG_OFF);
  float* ctx    = (float*)(ws + CTX_OFF);
  float* scores = (float*)(ws + SC_OFF);
  unsigned short* sideLoc = (unsigned short*)(ws + SL_OFF);
  float* sideGO = (float*)(ws + SG_OFF);

  hipFuncSetAttribute(reinterpret_cast<const void*>(gemm_fused),
                      hipFuncAttributeMaxDynamicSharedMemorySize, 114688);

  hipMemsetAsync(ws + MU_OFF, 0, 3 * 16384 + 256, stream);  // zero mu, u, v, cvec
  convert_mean_kernel<<<512, 256, 0, stream>>>(inp, W, inp_bf, w_bf, mu);

  void* cargs[10] = {(void*)&mu, (void*)&W, (void*)&bias, (void*)&inp_bf_c,
                     (void*)&agg, (void*)&v, (void*)&cvec, (void*)&scores,
                     (void*)&u, (void*)&ctx};
  hipLaunchCooperativeKernel((void*)chain_kernel, dim3(256), dim3(512), cargs, 0, stream);

  gemm_fused<<<512, 512, 114688, stream>>>((const __hip_bfloat16*)inp_bf,
                                           (const __hip_bfloat16*)w_bf,
                                           bias + 3 * A_, ctx, out, sideLoc, sideGO);
  fixup_kernel<<<64, 256, 0, stream>>>(sideLoc, sideGO, out);
}

// Round 8
// 133.622 us; speedup vs baseline: 1.9764x; 1.9764x over previous
//
#include <hip/hip_runtime.h>
#include <hip/hip_bf16.h>
#include <stdint.h>

#define B_    4
#define S_    4096
#define F_    1024
#define A_    512
#define N3_   1536
#define M_    16384

#define BM    256
#define BK    64
#define NT    (F_ / BK)   // 16 K-tiles
#define LDP   266         // Xt col-major stride (elems)

typedef __attribute__((ext_vector_type(8)))  __bf16 bf16x8;
typedef __attribute__((ext_vector_type(16))) float  f32x16;

#define MFMA32(a, b, c) __builtin_amdgcn_mfma_f32_32x32x16_bf16((a), (b), (c), 0, 0, 0)

// ---------- helpers ----------
__device__ __forceinline__ float bflo(unsigned int u) {
  union { unsigned int i; float f; } v; v.i = u << 16; return v.f;
}
__device__ __forceinline__ float bfhi(unsigned int u) {
  union { unsigned int i; float f; } v; v.i = u & 0xffff0000u; return v.f;
}
__device__ __forceinline__ float bf1(unsigned short u) {
  union { unsigned int i; float f; } v; v.i = ((unsigned int)u) << 16; return v.f;
}
__device__ __forceinline__ unsigned short bfc(float f) {
  return __builtin_bit_cast(unsigned short, __float2bfloat16(f));
}
__device__ __forceinline__ ushort4 cvt_bf4(float4 v) {
  ushort4 o;
  o.x = bfc(v.x); o.y = bfc(v.y); o.z = bfc(v.z); o.w = bfc(v.w);
  return o;
}

typedef __attribute__((address_space(3))) unsigned int lds_uint;
typedef const __attribute__((address_space(1))) unsigned int glob_uint;
__device__ __forceinline__ void lds_load16(const void* g, void* l) {
  __builtin_amdgcn_global_load_lds((glob_uint*)g, (lds_uint*)l, 16, 0, 0);
}

// ---------- K1: convert inp -> bf16 (+ column sums for mean), W[1536:3072] -> bf16 ----------
__global__ __launch_bounds__(256) void convert_mean_kernel(
    const float* __restrict__ inp, const float* __restrict__ W,
    unsigned short* __restrict__ inp_bf, unsigned short* __restrict__ w_bf,
    float* __restrict__ mu) {
  int blk = blockIdx.x;   // 512
  int t   = threadIdx.x;  // 256
  int r0  = blk * 32;
  int b   = r0 >> 12;
  float acc0 = 0.f, acc1 = 0.f, acc2 = 0.f, acc3 = 0.f;
  for (int r = 0; r < 32; r++) {
    size_t row = (size_t)(r0 + r);
    float4 v = ((const float4*)(inp + row * F_))[t];
    acc0 += v.x; acc1 += v.y; acc2 += v.z; acc3 += v.w;
    ((ushort4*)(inp_bf + row * F_))[t] = cvt_bf4(v);
  }
  atomicAdd(&mu[b * F_ + t * 4 + 0], acc0);
  atomicAdd(&mu[b * F_ + t * 4 + 1], acc1);
  atomicAdd(&mu[b * F_ + t * 4 + 2], acc2);
  atomicAdd(&mu[b * F_ + t * 4 + 3], acc3);

  const float* Wc = W + (size_t)N3_ * F_;
  const int n4 = (N3_ * F_) / 4;
  for (int i = blk * 256 + t; i < n4; i += 512 * 256) {
    ((ushort4*)w_bf)[i] = cvt_bf4(((const float4*)Wc)[i]);
  }
}

// ---------- K2: agg[b,a] = (mu[b,:]/S) . Wq[a,:] + b_q[a] ----------
__global__ void agg_kernel(const float* __restrict__ mu, const float* __restrict__ W,
                           const float* __restrict__ bias, float* __restrict__ agg) {
  int gw = blockIdx.x * 4 + (threadIdx.x >> 6);
  int lane = threadIdx.x & 63;
  int b = gw >> 9, a = gw & 511;
  const float4* wr = (const float4*)(W + (size_t)a * F_);
  const float4* mr = (const float4*)(mu + b * F_);
  float s = 0.f;
#pragma unroll
  for (int k = 0; k < 4; k++) {
    float4 wv = wr[lane + 64 * k], mv = mr[lane + 64 * k];
    s += wv.x * mv.x + wv.y * mv.y + wv.z * mv.z + wv.w * mv.w;
  }
  for (int off = 32; off; off >>= 1) s += __shfl_down(s, off);
  if (lane == 0) agg[b * A_ + a] = s * (1.f / S_) + bias[a];
}

// ---------- K3: v[b,f] += partial;  cvec[b] = agg[b,:].b_k ----------
__global__ void v_kernel(const float* __restrict__ agg, const float* __restrict__ W,
                         const float* __restrict__ bias, float* __restrict__ v,
                         float* __restrict__ cvec) {
  int fc = blockIdx.x;  // 0..3
  int ac = blockIdx.y;  // 0..7
  int t = threadIdx.x;
  int f = fc * 256 + t;
  const float* Wk = W + (size_t)A_ * F_;
  float s0 = 0.f, s1 = 0.f, s2 = 0.f, s3 = 0.f;
  int a0 = ac * 64;
  for (int a = a0; a < a0 + 64; a++) {
    float wv = Wk[(size_t)a * F_ + f];
    s0 += agg[a] * wv;
    s1 += agg[A_ + a] * wv;
    s2 += agg[2 * A_ + a] * wv;
    s3 += agg[3 * A_ + a] * wv;
  }
  atomicAdd(&v[f], s0);
  atomicAdd(&v[F_ + f], s1);
  atomicAdd(&v[2 * F_ + f], s2);
  atomicAdd(&v[3 * F_ + f], s3);

  if (fc == 0 && ac == 0) {
    int bb = t >> 6, l = t & 63;
    float c = 0.f;
#pragma unroll
    for (int i = 0; i < 8; i++) c += agg[bb * A_ + l + 64 * i] * bias[A_ + l + 64 * i];
    for (int off = 32; off; off >>= 1) c += __shfl_down(c, off);
    if (l == 0) cvec[bb] = c;
  }
}

// ---------- K4: scores[b,s] = v[b,:] . inp_bf[b,s,:] + c[b] ----------
__global__ void scores_kernel(const unsigned short* __restrict__ inp_bf,
                              const float* __restrict__ v,
                              const float* __restrict__ cvec, float* __restrict__ scores) {
  int lane = threadIdx.x & 63;
  int row = blockIdx.x * 4 + (threadIdx.x >> 6);
  int b = row >> 12;
  const uint4* ip = (const uint4*)(inp_bf + (size_t)row * F_);
  const float4* vp = (const float4*)(v + b * F_);
  float s = 0.f;
#pragma unroll
  for (int k = 0; k < 2; k++) {
    uint4 x = ip[lane + 64 * k];
    float4 va = vp[(lane + 64 * k) * 2];
    float4 vb = vp[(lane + 64 * k) * 2 + 1];
    s += bflo(x.x) * va.x + bfhi(x.x) * va.y + bflo(x.y) * va.z + bfhi(x.y) * va.w +
         bflo(x.z) * vb.x + bfhi(x.z) * vb.y + bflo(x.w) * vb.z + bfhi(x.w) * vb.w;
  }
  for (int off = 32; off; off >>= 1) s += __shfl_down(s, off);
  if (lane == 0) scores[row] = s + cvec[b];
}

// ---------- K5: softmax ----------
__global__ void softmax_kernel(float* __restrict__ sc) {
  __shared__ float red[256];
  int b = blockIdx.x, t = threadIdx.x;
  float* p = sc + b * S_;
  float vals[16];
  float m = -1e30f;
#pragma unroll
  for (int i = 0; i < 16; i++) { vals[i] = p[t + i * 256]; m = fmaxf(m, vals[i]); }
  red[t] = m; __syncthreads();
  for (int o = 128; o; o >>= 1) { if (t < o) red[t] = fmaxf(red[t], red[t + o]); __syncthreads(); }
  m = red[0]; __syncthreads();
  float sum = 0.f;
#pragma unroll
  for (int i = 0; i < 16; i++) { vals[i] = __expf(vals[i] - m); sum += vals[i]; }
  red[t] = sum; __syncthreads();
  for (int o = 128; o; o >>= 1) { if (t < o) red[t] += red[t + o]; __syncthreads(); }
  float inv = 1.f / red[0];
#pragma unroll
  for (int i = 0; i < 16; i++) p[t + i * 256] = vals[i] * inv;
}

// ---------- K6: u[b,f] = sum_s w[b,s] * inp_bf[b,s,f] ----------
__global__ void u_kernel(const unsigned short* __restrict__ inp_bf,
                         const float* __restrict__ w, float* __restrict__ u) {
  int b = blockIdx.z, fc = blockIdx.y, sc = blockIdx.x;
  int t = threadIdx.x;
  int f2 = fc * 512 + t * 2;
  int s0 = sc * 128;
  const float* wp = w + b * S_ + s0;
  const unsigned short* ip = inp_bf + ((size_t)(b * S_ + s0)) * F_ + f2;
  float a0 = 0.f, a1 = 0.f;
  for (int s = 0; s < 128; s++) {
    unsigned int xv = *(const unsigned int*)&ip[(size_t)s * F_];
    float ws = wp[s];
    a0 += ws * bflo(xv);
    a1 += ws * bfhi(xv);
  }
  atomicAdd(&u[b * F_ + f2], a0);
  atomicAdd(&u[b * F_ + f2 + 1], a1);
}

// ---------- K7: ctx[b,a] = u[b,:] . Wv[a,:] + b_v[a] ----------
__global__ void ctx_kernel(const float* __restrict__ u, const float* __restrict__ W,
                           const float* __restrict__ bias, float* __restrict__ ctx) {
  int gw = blockIdx.x * 4 + (threadIdx.x >> 6);
  int lane = threadIdx.x & 63;
  int b = gw >> 9, a = gw & 511;
  const float4* wr = (const float4*)(W + (size_t)(2 * A_ + a) * F_);
  const float4* ur = (const float4*)(u + b * F_);
  float s = 0.f;
#pragma unroll
  for (int k = 0; k < 4; k++) {
    float4 wv = wr[lane + 64 * k], uv = ur[lane + 64 * k];
    s += wv.x * uv.x + wv.y * uv.y + wv.z * uv.z + wv.w * uv.w;
  }
  for (int off = 32; off; off >>= 1) s += __shfl_down(s, off);
  if (lane == 0) ctx[b * A_ + a] = s + bias[2 * A_ + a];
}

// ---------- K8: fused GEMM (32x32x16 MFMA, 2-barrier counted-vmcnt loop) + final ----------
__global__ __launch_bounds__(512, 2) void gemm_fused(
    const __hip_bfloat16* __restrict__ Abf,
    const __hip_bfloat16* __restrict__ Wbf,
    const float* __restrict__ biasP,   // bias + 1536
    const float* __restrict__ ctx,
    float* __restrict__ out,
    unsigned short* __restrict__ sideLoc,
    float* __restrict__ sideGO) {
  extern __shared__ unsigned short smem[];
  unsigned short* ldsA = smem;            // 2 x 16384 elems
  unsigned short* ldsB = smem + 32768;    // 2 x 12288 elems
  unsigned short* Xt   = smem;            // epilogue alias: [192 cols][266 rows]
  float* segred = (float*)((char*)smem + 192 * LDP * 2);  // 4 x 64 f32

  int bid = blockIdx.x;
  int swz = (bid & 7) * 64 + (bid >> 3);  // 512 blocks, 8 XCDs, bijective
  int mb = swz >> 3;   // 0..63
  int nb = swz & 7;    // 0..7

  int tid  = threadIdx.x;
  int lane = tid & 63;
  int wv   = tid >> 6;       // 0..7
  int wm   = wv >> 1;        // 0..3 : 64-row slice
  int wn   = wv & 1;         // 0..1 : 96-col slice
  int l31  = lane & 31, half = lane >> 5, r7 = l31 & 7;

  // swizzled in-row element offsets for the 4 k-slices of 16 (slot = ks*2+half, XOR row&7)
  int eo[4];
#pragma unroll
  for (int ks = 0; ks < 4; ks++) eo[ks] = ((ks * 2 + half) ^ r7) * 8;

  const __hip_bfloat16* Ab = Abf + (size_t)mb * BM * F_;

  int srow = tid >> 3;                       // 0..63
  int sel  = ((tid & 7) ^ (srow & 7)) * 8;
  int ldst = wv * 512;

  const f32x16 zero16 = {0.f,0.f,0.f,0.f,0.f,0.f,0.f,0.f,0.f,0.f,0.f,0.f,0.f,0.f,0.f,0.f};
  f32x16 acc[2][3];
#pragma unroll
  for (int i = 0; i < 2; i++)
#pragma unroll
    for (int j = 0; j < 3; j++) acc[i][j] = zero16;

  int aRowBase = (wm * 64 + l31) * 64;   // + fi*32 rows -> +fi*2048 elems
  int bRowBase = (wn * 96 + l31) * 64;   // + fj*32 rows -> +fj*2048 elems

#define STG_A(kt_, buf_, r_)                                                              \
  lds_load16(Ab + (size_t)((r_) * 64 + srow) * F_ + (kt_) * BK + sel,                     \
             ldsA + (buf_) * 16384 + (r_) * 4096 + ldst)
#define STG_B(kt_, buf_, q_)                                                              \
  lds_load16(Wbf + (size_t)((q_) * 512 + nb * 64 + srow) * F_ + (kt_) * BK + sel,         \
             ldsB + (buf_) * 12288 + (q_) * 4096 + ldst)

  // prologue: stage tile 0 (7 loads)
  STG_A(0, 0, 0); STG_A(0, 0, 1); STG_A(0, 0, 2); STG_A(0, 0, 3);
  STG_B(0, 0, 0); STG_B(0, 0, 1); STG_B(0, 0, 2);

  for (int kt = 0; kt < NT; ++kt) {
    int c = kt & 1, nx = c ^ 1;
    bool pf = (kt + 1 < NT);
    const unsigned short* la = ldsA + c * 16384;
    const unsigned short* lb = ldsB + c * 12288;

    __builtin_amdgcn_s_barrier();            // all waves done reading buf nx (prev tile)
    if (pf) {
      STG_A(kt + 1, nx, 0); STG_A(kt + 1, nx, 1); STG_A(kt + 1, nx, 2); STG_A(kt + 1, nx, 3);
      asm volatile("s_waitcnt vmcnt(4)" ::: "memory");   // tile-kt's 7 loads landed
    } else {
      asm volatile("s_waitcnt vmcnt(0)" ::: "memory");
    }
    __builtin_amdgcn_s_barrier();            // buf c visible to all waves

    bf16x8 a0[2][2], b0[3][2];
    // ---- ks-slices 0,1 : reads + 12 MFMA (compiler fine-schedules lgkm waits)
#pragma unroll
    for (int fi = 0; fi < 2; fi++)
#pragma unroll
      for (int ks = 0; ks < 2; ks++)
        a0[fi][ks] = *(const bf16x8*)&la[aRowBase + fi * 2048 + eo[ks]];
#pragma unroll
    for (int fj = 0; fj < 3; fj++)
#pragma unroll
      for (int ks = 0; ks < 2; ks++)
        b0[fj][ks] = *(const bf16x8*)&lb[bRowBase + fj * 2048 + eo[ks]];
    __builtin_amdgcn_s_setprio(1);
#pragma unroll
    for (int ks = 0; ks < 2; ks++)
#pragma unroll
      for (int fi = 0; fi < 2; fi++)
#pragma unroll
        for (int fj = 0; fj < 3; fj++)
          acc[fi][fj] = MFMA32(a0[fi][ks], b0[fj][ks], acc[fi][fj]);
    __builtin_amdgcn_s_setprio(0);

    if (pf) { STG_B(kt + 1, nx, 0); STG_B(kt + 1, nx, 1); STG_B(kt + 1, nx, 2); }

    // ---- ks-slices 2,3
#pragma unroll
    for (int fi = 0; fi < 2; fi++)
#pragma unroll
      for (int ks = 0; ks < 2; ks++)
        a0[fi][ks] = *(const bf16x8*)&la[aRowBase + fi * 2048 + eo[2 + ks]];
#pragma unroll
    for (int fj = 0; fj < 3; fj++)
#pragma unroll
      for (int ks = 0; ks < 2; ks++)
        b0[fj][ks] = *(const bf16x8*)&lb[bRowBase + fj * 2048 + eo[2 + ks]];
    __builtin_amdgcn_s_setprio(1);
#pragma unroll
    for (int ks = 0; ks < 2; ks++)
#pragma unroll
      for (int fi = 0; fi < 2; fi++)
#pragma unroll
        for (int fj = 0; fj < 3; fj++)
          acc[fi][fj] = MFMA32(a0[fi][ks], b0[fj][ks], acc[fi][fj]);
    __builtin_amdgcn_s_setprio(0);
  }
#undef STG_A
#undef STG_B

  __syncthreads();   // all waves done with staging LDS before Xt overwrite

  // ---------------- epilogue ----------------
  // acc (+bias) -> Xt col-major bf16. C/D: col=lane&31, row=(reg&3)+8*(reg>>2)+4*half.
  float bias_r[3];
#pragma unroll
  for (int fj = 0; fj < 3; fj++) {
    int cl = wn * 96 + fj * 32 + l31;
    bias_r[fj] = biasP[(cl >> 6) * 512 + nb * 64 + (cl & 63)];
  }
#pragma unroll
  for (int fi = 0; fi < 2; fi++) {
#pragma unroll
    for (int fj = 0; fj < 3; fj++) {
      int cl = wn * 96 + fj * 32 + l31;
      int rbase = wm * 64 + fi * 32 + half * 4;
#pragma unroll
      for (int q = 0; q < 4; q++) {
        int r = rbase + q * 8;
        float v0 = acc[fi][fj][4 * q + 0] + bias_r[fj];
        float v1 = acc[fi][fj][4 * q + 1] + bias_r[fj];
        float v2 = acc[fi][fj][4 * q + 2] + bias_r[fj];
        float v3 = acc[fi][fj][4 * q + 3] + bias_r[fj];
        unsigned int u01 = (unsigned int)bfc(v0) | ((unsigned int)bfc(v1) << 16);
        unsigned int u23 = (unsigned int)bfc(v2) | ((unsigned int)bfc(v3) << 16);
        *(unsigned int*)&Xt[cl * LDP + r]     = u01;
        *(unsigned int*)&Xt[cl * LDP + r + 2] = u23;
      }
    }
  }
  __syncthreads();

  // segment maxes: seg strip = Xt cols 0..63
  if (tid < 256) {
    int seg = tid >> 6, c = tid & 63;
    int base = c * LDP + seg * 64;
    float m = -1e30f;
#pragma unroll
    for (int k = 0; k < 32; k++) {
      unsigned int uu = *(const unsigned int*)&Xt[base + 2 * k];
      m = fmaxf(m, fmaxf(bflo(uu), bfhi(uu)));
    }
    segred[seg * 64 + c] = m;
  }
  __syncthreads();

  // final combine: wave wv owns rows wv*32..+31, lane = col c (0..63)
  {
    int c  = lane;
    int r0 = wv * 32;
    int b  = mb >> 4;
    int gcol = nb * 64 + c;
    float g = ctx[b * 512 + gcol] + segred[(r0 >> 6) * 64 + c];
    int lbase = (64 + c) * LDP;
    int obase = (128 + c) * LDP;
    float lw0 = bf1(Xt[lbase + max(r0 - 2, 0)]);
    float lw1 = bf1(Xt[lbase + max(r0 - 1, 0)]);
    float lw2 = bf1(Xt[lbase + r0]);
    float lw3 = bf1(Xt[lbase + r0 + 1]);
    size_t obase_g = ((size_t)(mb * 256 + r0)) * 512 + gcol;
#pragma unroll
    for (int j = 0; j < 32; j++) {
      int rn = min(r0 + j + 2, 255);
      float lw4 = bf1(Xt[lbase + rn]);
      float lm = fmaxf(fmaxf(fmaxf(lw0, lw1), fmaxf(lw2, lw3)), lw4);
      float o = bf1(Xt[obase + r0 + j]);
      out[obase_g + (size_t)j * 512] = g * o + lm;
      lw0 = lw1; lw1 = lw2; lw2 = lw3; lw3 = lw4;
    }
  }

  // side buffers for tile-boundary loc-window fixup (rows 0,1,254,255)
  if (tid < 256) {
    int rsel = tid >> 6, c = tid & 63;
    int r = (rsel < 2) ? rsel : (252 + rsel);   // 0,1,254,255
    int b = mb >> 4;
    float g = ctx[b * 512 + nb * 64 + c] + segred[(r >> 6) * 64 + c];
    float o = bf1(Xt[(128 + c) * LDP + r]);
    int gr = mb * 4 + rsel;
    sideLoc[gr * 512 + nb * 64 + c] = Xt[(64 + c) * LDP + r];
    sideGO[gr * 512 + nb * 64 + c]  = g * o;
  }
}

// ---------- K9: fixup for loc windows crossing 256-row tile boundaries ----------
__global__ void fixup_kernel(const unsigned short* __restrict__ sideLoc,
                             const float* __restrict__ sideGO,
                             float* __restrict__ out) {
  int rb = blockIdx.x;      // 0..63
  int tb = rb & 15;         // tile index within b
  int t = threadIdx.x;      // 256
  int rsel = t >> 6, cq = t & 63;
#pragma unroll
  for (int k = 0; k < 8; k++) {
    int c = cq * 8 + k;
    float miss;
    int rl;
    if (rsel == 0) {
      if (tb == 0) continue;
      miss = fmaxf(bf1(sideLoc[((rb - 1) * 4 + 2) * 512 + c]),
                   bf1(sideLoc[((rb - 1) * 4 + 3) * 512 + c]));
      rl = 0;
    } else if (rsel == 1) {
      if (tb == 0) continue;
      miss = bf1(sideLoc[((rb - 1) * 4 + 3) * 512 + c]);
      rl = 1;
    } else if (rsel == 2) {
      if (tb == 15) continue;
      miss = bf1(sideLoc[((rb + 1) * 4 + 0) * 512 + c]);
      rl = 254;
    } else {
      if (tb == 15) continue;
      miss = fmaxf(bf1(sideLoc[((rb + 1) * 4 + 0) * 512 + c]),
                   bf1(sideLoc[((rb + 1) * 4 + 1) * 512 + c]));
      rl = 255;
    }
    size_t oi = ((size_t)rb * 256 + rl) * 512 + c;
    float cand = sideGO[(rb * 4 + rsel) * 512 + c] + miss;
    out[oi] = fmaxf(out[oi], cand);
  }
}

// ---------- launch ----------
extern "C" void kernel_launch(void* const* d_in, const int* in_sizes, int n_in,
                              void* d_out, int out_size, void* d_ws, size_t ws_size,
                              hipStream_t stream) {
  const float* inp  = (const float*)d_in[0];
  const float* W    = (const float*)d_in[1];
  const float* bias = (const float*)d_in[2];
  float* out = (float*)d_out;
  char* ws = (char*)d_ws;

  const size_t INP_OFF  = 0;                   // bf16 inp: 33,554,432
  const size_t W_OFF    = 33554432;            // bf16 W[1536:3072]: 3,145,728
  const size_t MU_OFF   = 36700160;            // f32 mu: 16,384
  const size_t U_OFF    = MU_OFF + 16384;
  const size_t V_OFF    = U_OFF + 16384;
  const size_t CV_OFF   = V_OFF + 16384;       // 256
  const size_t AGG_OFF  = CV_OFF + 256;        // 8,192
  const size_t CTX_OFF  = AGG_OFF + 8192;      // 8,192
  const size_t SC_OFF   = CTX_OFF + 8192;      // 65,536
  const size_t SL_OFF   = SC_OFF + 65536;      // sideLoc bf16: 262,144
  const size_t SG_OFF   = SL_OFF + 262144;     // sideGO f32: 524,288

  unsigned short* inp_bf = (unsigned short*)(ws + INP_OFF);
  unsigned short* w_bf   = (unsigned short*)(ws + W_OFF);
  float* mu     = (float*)(ws + MU_OFF);
  float* u      = (float*)(ws + U_OFF);
  float* v      = (float*)(ws + V_OFF);
  float* cvec   = (float*)(ws + CV_OFF);
  float* agg    = (float*)(ws + AGG_OFF);
  float* ctx    = (float*)(ws + CTX_OFF);
  float* scores = (float*)(ws + SC_OFF);
  unsigned short* sideLoc = (unsigned short*)(ws + SL_OFF);
  float* sideGO = (float*)(ws + SG_OFF);

  hipFuncSetAttribute(reinterpret_cast<const void*>(gemm_fused),
                      hipFuncAttributeMaxDynamicSharedMemorySize, 114688);

  hipMemsetAsync(ws + MU_OFF, 0, 3 * 16384 + 256, stream);  // zero mu, u, v, cvec
  convert_mean_kernel<<<512, 256, 0, stream>>>(inp, W, inp_bf, w_bf, mu);
  agg_kernel<<<512, 256, 0, stream>>>(mu, W, bias, agg);
  v_kernel<<<dim3(4, 8), 256, 0, stream>>>(agg, W, bias, v, cvec);
  scores_kernel<<<4096, 256, 0, stream>>>(inp_bf, v, cvec, scores);
  softmax_kernel<<<4, 256, 0, stream>>>(scores);
  u_kernel<<<dim3(32, 2, 4), 256, 0, stream>>>(inp_bf, scores, u);
  ctx_kernel<<<512, 256, 0, stream>>>(u, W, bias, ctx);
  gemm_fused<<<512, 512, 114688, stream>>>((const __hip_bfloat16*)inp_bf,
                                           (const __hip_bfloat16*)w_bf,
                                           bias + 3 * A_, ctx, out, sideLoc, sideGO);
  fixup_kernel<<<64, 256, 0, stream>>>(sideLoc, sideGO, out);
}

// Round 9
// 128.173 us; speedup vs baseline: 2.0604x; 1.0425x over previous
//
#include <hip/hip_runtime.h>
#include <hip/hip_bf16.h>
#include <stdint.h>

#define B_    4
#define S_    4096
#define F_    1024
#define A_    512
#define N3_   1536
#define M_    16384

#define BM    256
#define BK    64
#define NT    (F_ / BK)   // 16 K-tiles
#define LDP   266         // Xt col-major stride (elems)

typedef __attribute__((ext_vector_type(8))) __bf16 bf16x8;

#define MFMA(a, b, c) __builtin_amdgcn_mfma_f32_16x16x32_bf16((a), (b), (c), 0, 0, 0)
typedef __attribute__((ext_vector_type(4))) float f32x4;

// ---------- helpers ----------
__device__ __forceinline__ float bflo(unsigned int u) {
  union { unsigned int i; float f; } v; v.i = u << 16; return v.f;
}
__device__ __forceinline__ float bfhi(unsigned int u) {
  union { unsigned int i; float f; } v; v.i = u & 0xffff0000u; return v.f;
}
__device__ __forceinline__ float bf1(unsigned short u) {
  union { unsigned int i; float f; } v; v.i = ((unsigned int)u) << 16; return v.f;
}
__device__ __forceinline__ unsigned short bfc(float f) {
  return __builtin_bit_cast(unsigned short, __float2bfloat16(f));
}
__device__ __forceinline__ ushort4 cvt_bf4(float4 v) {
  ushort4 o;
  o.x = bfc(v.x); o.y = bfc(v.y); o.z = bfc(v.z); o.w = bfc(v.w);
  return o;
}

typedef __attribute__((address_space(3))) unsigned int lds_uint;
typedef const __attribute__((address_space(1))) unsigned int glob_uint;
__device__ __forceinline__ void lds_load16(const void* g, void* l) {
  __builtin_amdgcn_global_load_lds((glob_uint*)g, (lds_uint*)l, 16, 0, 0);
}

// ---------- K1: convert inp -> bf16 (+ column sums for mean), W[1536:3072] -> bf16 ----------
__global__ __launch_bounds__(256) void convert_mean_kernel(
    const float* __restrict__ inp, const float* __restrict__ W,
    unsigned short* __restrict__ inp_bf, unsigned short* __restrict__ w_bf,
    float* __restrict__ mu) {
  int blk = blockIdx.x;   // 512
  int t   = threadIdx.x;  // 256
  int r0  = blk * 32;
  int b   = r0 >> 12;
  float acc0 = 0.f, acc1 = 0.f, acc2 = 0.f, acc3 = 0.f;
  for (int r = 0; r < 32; r++) {
    size_t row = (size_t)(r0 + r);
    float4 v = ((const float4*)(inp + row * F_))[t];
    acc0 += v.x; acc1 += v.y; acc2 += v.z; acc3 += v.w;
    ((ushort4*)(inp_bf + row * F_))[t] = cvt_bf4(v);
  }
  atomicAdd(&mu[b * F_ + t * 4 + 0], acc0);
  atomicAdd(&mu[b * F_ + t * 4 + 1], acc1);
  atomicAdd(&mu[b * F_ + t * 4 + 2], acc2);
  atomicAdd(&mu[b * F_ + t * 4 + 3], acc3);

  const float* Wc = W + (size_t)N3_ * F_;
  const int n4 = (N3_ * F_) / 4;
  for (int i = blk * 256 + t; i < n4; i += 512 * 256) {
    ((ushort4*)w_bf)[i] = cvt_bf4(((const float4*)Wc)[i]);
  }
}

// ---------- K2: agg[b,a] = (mu[b,:]/S) . Wq[a,:] + b_q[a] ----------
__global__ void agg_kernel(const float* __restrict__ mu, const float* __restrict__ W,
                           const float* __restrict__ bias, float* __restrict__ agg) {
  int gw = blockIdx.x * 4 + (threadIdx.x >> 6);
  int lane = threadIdx.x & 63;
  int b = gw >> 9, a = gw & 511;
  const float4* wr = (const float4*)(W + (size_t)a * F_);
  const float4* mr = (const float4*)(mu + b * F_);
  float s = 0.f;
#pragma unroll
  for (int k = 0; k < 4; k++) {
    float4 wv = wr[lane + 64 * k], mv = mr[lane + 64 * k];
    s += wv.x * mv.x + wv.y * mv.y + wv.z * mv.z + wv.w * mv.w;
  }
  for (int off = 32; off; off >>= 1) s += __shfl_down(s, off);
  if (lane == 0) agg[b * A_ + a] = s * (1.f / S_) + bias[a];
}

// ---------- K3: v[b,f] += sum_{a in chunk} agg[b,a]*Wk[a,f]  (cvec dropped: cancels in softmax) ----------
__global__ void v_kernel(const float* __restrict__ agg, const float* __restrict__ W,
                         float* __restrict__ v) {
  int fc = blockIdx.x;  // 0..3
  int ac = blockIdx.y;  // 0..7
  int t = threadIdx.x;
  int f = fc * 256 + t;
  const float* Wk = W + (size_t)A_ * F_;
  float s0 = 0.f, s1 = 0.f, s2 = 0.f, s3 = 0.f;
  int a0 = ac * 64;
  for (int a = a0; a < a0 + 64; a++) {
    float wv = Wk[(size_t)a * F_ + f];
    s0 += agg[a] * wv;
    s1 += agg[A_ + a] * wv;
    s2 += agg[2 * A_ + a] * wv;
    s3 += agg[3 * A_ + a] * wv;
  }
  atomicAdd(&v[f], s0);
  atomicAdd(&v[F_ + f], s1);
  atomicAdd(&v[2 * F_ + f], s2);
  atomicAdd(&v[3 * F_ + f], s3);
}

// ---------- K4: fused scores + online-softmax + weighted-sum partials ----------
// One block = one 64-row s-chunk of one batch. Produces uP[chunk][1024] (unnormalized
// exp-weighted sum) and mlzl[chunk] = {local max, local Z}.
__global__ __launch_bounds__(256) void scores_u_kernel(
    const unsigned short* __restrict__ inp_bf, const float* __restrict__ v,
    float* __restrict__ uP, float* __restrict__ mlzl) {
  int blk = blockIdx.x;            // 0..255
  int b = blk >> 6, ch = blk & 63;
  int s0 = ch * 64;
  int t = threadIdx.x, lane = t & 63, wv = t >> 6;   // 4 waves
  __shared__ float sc[64];
  __shared__ float wsl[64];

  // phase 1: scores for rows wv*16 .. wv*16+15 (one wave-dot per row)
  const float4* vp = (const float4*)(v + b * F_);
  float4 va0 = vp[lane * 2], va1 = vp[lane * 2 + 1];
  float4 vb0 = vp[(lane + 64) * 2], vb1 = vp[(lane + 64) * 2 + 1];
#pragma unroll
  for (int i = 0; i < 16; i++) {
    int r = wv * 16 + i;
    const uint4* ip = (const uint4*)(inp_bf + ((size_t)(b * S_ + s0 + r)) * F_);
    uint4 x0 = ip[lane], x1 = ip[lane + 64];
    float s = bflo(x0.x) * va0.x + bfhi(x0.x) * va0.y + bflo(x0.y) * va0.z + bfhi(x0.y) * va0.w +
              bflo(x0.z) * va1.x + bfhi(x0.z) * va1.y + bflo(x0.w) * va1.z + bfhi(x0.w) * va1.w +
              bflo(x1.x) * vb0.x + bfhi(x1.x) * vb0.y + bflo(x1.y) * vb0.z + bfhi(x1.y) * vb0.w +
              bflo(x1.z) * vb1.x + bfhi(x1.z) * vb1.y + bflo(x1.w) * vb1.z + bfhi(x1.w) * vb1.w;
    for (int off = 32; off; off >>= 1) s += __shfl_down(s, off);
    if (lane == 0) sc[r] = s;
  }
  __syncthreads();

  // phase 2: local max (redundant per thread, deterministic), exp weights
  float m = -1e30f;
#pragma unroll
  for (int i = 0; i < 64; i++) m = fmaxf(m, sc[i]);
  if (t < 64) wsl[t] = __expf(sc[t] - m);
  __syncthreads();

  // phase 3: u partial: thread t handles f = t*4..t*4+3
  {
    const unsigned short* xp = inp_bf + ((size_t)(b * S_ + s0)) * F_ + t * 4;
    float a0 = 0.f, a1 = 0.f, a2 = 0.f, a3 = 0.f;
    for (int s = 0; s < 64; s++) {
      uint2 xv = *(const uint2*)&xp[(size_t)s * F_];
      float w = wsl[s];
      a0 += w * bflo(xv.x); a1 += w * bfhi(xv.x);
      a2 += w * bflo(xv.y); a3 += w * bfhi(xv.y);
    }
    float4 o; o.x = a0; o.y = a1; o.z = a2; o.w = a3;
    *(float4*)&uP[(size_t)blk * 1024 + t * 4] = o;
  }
  if (t == 0) {
    float Z = 0.f;
#pragma unroll
    for (int i = 0; i < 64; i++) Z += wsl[i];
    mlzl[blk * 2] = m; mlzl[blk * 2 + 1] = Z;
  }
}

// ---------- K5: finalize u (flash-style combine of 64 chunk partials per batch) ----------
__global__ void ufin_kernel(const float* __restrict__ uP, const float* __restrict__ mlzl,
                            float* __restrict__ u) {
  int b = blockIdx.x >> 2, fs = blockIdx.x & 3;   // 16 blocks
  int f = fs * 256 + threadIdx.x;
  float M = -1e30f;
#pragma unroll
  for (int i = 0; i < 64; i++) M = fmaxf(M, mlzl[(b * 64 + i) * 2]);
  float Z = 0.f;
#pragma unroll
  for (int i = 0; i < 64; i++) Z += __expf(mlzl[(b * 64 + i) * 2] - M) * mlzl[(b * 64 + i) * 2 + 1];
  float acc = 0.f;
  for (int ch = 0; ch < 64; ch++) {
    float sc = __expf(mlzl[(b * 64 + ch) * 2] - M);
    acc += sc * uP[(size_t)(b * 64 + ch) * 1024 + f];
  }
  u[b * F_ + f] = acc / Z;
}

// ---------- K6: ctx[b,a] = u[b,:] . Wv[a,:] + b_v[a] ----------
__global__ void ctx_kernel(const float* __restrict__ u, const float* __restrict__ W,
                           const float* __restrict__ bias, float* __restrict__ ctx) {
  int gw = blockIdx.x * 4 + (threadIdx.x >> 6);
  int lane = threadIdx.x & 63;
  int b = gw >> 9, a = gw & 511;
  const float4* wr = (const float4*)(W + (size_t)(2 * A_ + a) * F_);
  const float4* ur = (const float4*)(u + b * F_);
  float s = 0.f;
#pragma unroll
  for (int k = 0; k < 4; k++) {
    float4 wv = wr[lane + 64 * k], uv = ur[lane + 64 * k];
    s += wv.x * uv.x + wv.y * uv.y + wv.z * uv.z + wv.w * uv.w;
  }
  for (int off = 32; off; off >>= 1) s += __shfl_down(s, off);
  if (lane == 0) ctx[b * A_ + a] = s + bias[2 * A_ + a];
}

// ---------- K7: fused GEMM + final, pipelined 3-phase (R6 proven: 54us, 16x16 MFMA) ----------
__global__ __launch_bounds__(512, 2) void gemm_fused(
    const __hip_bfloat16* __restrict__ Abf,
    const __hip_bfloat16* __restrict__ Wbf,
    const float* __restrict__ biasP,   // bias + 1536
    const float* __restrict__ ctx,
    float* __restrict__ out,
    unsigned short* __restrict__ sideLoc,
    float* __restrict__ sideGO) {
  extern __shared__ unsigned short smem[];
  unsigned short* ldsA = smem;            // 2 x 16384 elems
  unsigned short* ldsB = smem + 32768;    // 2 x 12288 elems
  unsigned short* Xt   = smem;            // epilogue alias: [192 cols][266 rows]
  float* segred = (float*)((char*)smem + 192 * LDP * 2);  // 4 x 64 f32

  int bid = blockIdx.x;
  int swz = (bid & 7) * 64 + (bid >> 3);  // 512 blocks, 8 XCDs, bijective
  int mb = swz >> 3;   // 0..63
  int nb = swz & 7;    // 0..7

  int tid  = threadIdx.x;
  int lane = tid & 63;
  int wv   = tid >> 6;       // 0..7
  int wm   = wv >> 1;        // 0..3 : 64-row slice
  int wn   = wv & 1;         // 0..1 : 96-col slice
  int lo   = lane & 15, hi = lane >> 4, sw = lane & 7;

  int bir0 = (((hi * 16)      ^ (sw << 4)) >> 1);
  int bir1 = (((64 + hi * 16) ^ (sw << 4)) >> 1);

  const __hip_bfloat16* Ab = Abf + (size_t)mb * BM * F_;

  int srow = tid >> 3;                       // 0..63
  int sel  = ((tid & 7) ^ (srow & 7)) * 8;
  int ldst = wv * 512;

  f32x4 acc[4][6];
#pragma unroll
  for (int i = 0; i < 4; i++)
#pragma unroll
    for (int j = 0; j < 6; j++) acc[i][j] = (f32x4){0.f, 0.f, 0.f, 0.f};

  int aBase = (wm * 64 + lo) * 64;
  int bBase = (wn * 96 + lo) * 64;

#define STG_A(kt_, buf_, r_)                                                              \
  lds_load16(Ab + (size_t)((r_) * 64 + srow) * F_ + (kt_) * BK + sel,                     \
             ldsA + (buf_) * 16384 + (r_) * 4096 + ldst)
#define STG_B(kt_, buf_, q_)                                                              \
  lds_load16(Wbf + (size_t)((q_) * 512 + nb * 64 + srow) * F_ + (kt_) * BK + sel,         \
             ldsB + (buf_) * 12288 + (q_) * 4096 + ldst)

  bf16x8 af[4][2], b01[2][2], b23[2][2], b45[2][2];

  // prologue: stage tile 0, wait, read A + B01 of tile 0
  STG_A(0, 0, 0); STG_A(0, 0, 1); STG_A(0, 0, 2); STG_A(0, 0, 3);
  STG_B(0, 0, 0); STG_B(0, 0, 1); STG_B(0, 0, 2);
  asm volatile("s_waitcnt vmcnt(0)" ::: "memory");
  __builtin_amdgcn_s_barrier();
#pragma unroll
  for (int i = 0; i < 4; i++) {
    af[i][0] = *(const bf16x8*)&ldsA[aBase + i * 1024 + bir0];
    af[i][1] = *(const bf16x8*)&ldsA[aBase + i * 1024 + bir1];
  }
#pragma unroll
  for (int j = 0; j < 2; j++) {
    b01[j][0] = *(const bf16x8*)&ldsB[bBase + j * 1024 + bir0];
    b01[j][1] = *(const bf16x8*)&ldsB[bBase + j * 1024 + bir1];
  }

  for (int kt = 0; kt < NT; ++kt) {
    int c = kt & 1, nx = c ^ 1;
    bool pf = (kt + 1 < NT);
    const unsigned short* lb  = ldsB + c * 12288;
    const unsigned short* lan = ldsA + nx * 16384;
    const unsigned short* lbn = ldsB + nx * 12288;

    // ---- phase 0: stage next A; MFMA A x B01; issue B23 reads; barrier
    if (pf) { STG_A(kt + 1, nx, 0); STG_A(kt + 1, nx, 1); STG_A(kt + 1, nx, 2); STG_A(kt + 1, nx, 3); }
    asm volatile("s_waitcnt lgkmcnt(0)" ::: "memory");
    __builtin_amdgcn_sched_barrier(0);
    __builtin_amdgcn_s_setprio(1);
#pragma unroll
    for (int i = 0; i < 4; i++)
#pragma unroll
      for (int j = 0; j < 2; j++) {
        acc[i][j] = MFMA(af[i][0], b01[j][0], acc[i][j]);
        acc[i][j] = MFMA(af[i][1], b01[j][1], acc[i][j]);
      }
    __builtin_amdgcn_s_setprio(0);
#pragma unroll
    for (int j = 0; j < 2; j++) {
      b23[j][0] = *(const bf16x8*)&lb[bBase + (2 + j) * 1024 + bir0];
      b23[j][1] = *(const bf16x8*)&lb[bBase + (2 + j) * 1024 + bir1];
    }
    __builtin_amdgcn_s_barrier();

    // ---- phase 1: stage next B; MFMA A x B23; issue B45 reads; barrier
    if (pf) { STG_B(kt + 1, nx, 0); STG_B(kt + 1, nx, 1); STG_B(kt + 1, nx, 2); }
    asm volatile("s_waitcnt lgkmcnt(0)" ::: "memory");
    __builtin_amdgcn_sched_barrier(0);
    __builtin_amdgcn_s_setprio(1);
#pragma unroll
    for (int i = 0; i < 4; i++)
#pragma unroll
      for (int j = 0; j < 2; j++) {
        acc[i][2 + j] = MFMA(af[i][0], b23[j][0], acc[i][2 + j]);
        acc[i][2 + j] = MFMA(af[i][1], b23[j][1], acc[i][2 + j]);
      }
    __builtin_amdgcn_s_setprio(0);
#pragma unroll
    for (int j = 0; j < 2; j++) {
      b45[j][0] = *(const bf16x8*)&lb[bBase + (4 + j) * 1024 + bir0];
      b45[j][1] = *(const bf16x8*)&lb[bBase + (4 + j) * 1024 + bir1];
    }
    __builtin_amdgcn_s_barrier();

    // ---- phase 2: MFMA A x B45; vmcnt; barrier; read next tile's A + B01
    asm volatile("s_waitcnt lgkmcnt(0)" ::: "memory");
    __builtin_amdgcn_sched_barrier(0);
    __builtin_amdgcn_s_setprio(1);
#pragma unroll
    for (int i = 0; i < 4; i++)
#pragma unroll
      for (int j = 0; j < 2; j++) {
        acc[i][4 + j] = MFMA(af[i][0], b45[j][0], acc[i][4 + j]);
        acc[i][4 + j] = MFMA(af[i][1], b45[j][1], acc[i][4 + j]);
      }
    __builtin_amdgcn_s_setprio(0);
    if (pf) asm volatile("s_waitcnt vmcnt(0)" ::: "memory");
    __builtin_amdgcn_s_barrier();
    if (pf) {
#pragma unroll
      for (int i = 0; i < 4; i++) {
        af[i][0] = *(const bf16x8*)&lan[aBase + i * 1024 + bir0];
        af[i][1] = *(const bf16x8*)&lan[aBase + i * 1024 + bir1];
      }
#pragma unroll
      for (int j = 0; j < 2; j++) {
        b01[j][0] = *(const bf16x8*)&lbn[bBase + j * 1024 + bir0];
        b01[j][1] = *(const bf16x8*)&lbn[bBase + j * 1024 + bir1];
      }
    }
  }
#undef STG_A
#undef STG_B

  // ---------------- epilogue ----------------
  float bias_r[6];
#pragma unroll
  for (int fj = 0; fj < 6; fj++) {
    int cl = wn * 96 + fj * 16 + lo;
    bias_r[fj] = biasP[(cl >> 6) * 512 + nb * 64 + (cl & 63)];
  }
#pragma unroll
  for (int fi = 0; fi < 4; fi++) {
#pragma unroll
    for (int fj = 0; fj < 6; fj++) {
      int cl = wn * 96 + fj * 16 + lo;
      int r  = wm * 64 + fi * 16 + hi * 4;
      float v0 = acc[fi][fj][0] + bias_r[fj];
      float v1 = acc[fi][fj][1] + bias_r[fj];
      float v2 = acc[fi][fj][2] + bias_r[fj];
      float v3 = acc[fi][fj][3] + bias_r[fj];
      unsigned int u01 = (unsigned int)bfc(v0) | ((unsigned int)bfc(v1) << 16);
      unsigned int u23 = (unsigned int)bfc(v2) | ((unsigned int)bfc(v3) << 16);
      *(unsigned int*)&Xt[cl * LDP + r]     = u01;
      *(unsigned int*)&Xt[cl * LDP + r + 2] = u23;
    }
  }
  __syncthreads();

  // segment maxes: seg strip = Xt cols 0..63
  if (tid < 256) {
    int seg = tid >> 6, c = tid & 63;
    int base = c * LDP + seg * 64;
    float m = -1e30f;
#pragma unroll
    for (int k = 0; k < 32; k++) {
      unsigned int uu = *(const unsigned int*)&Xt[base + 2 * k];
      m = fmaxf(m, fmaxf(bflo(uu), bfhi(uu)));
    }
    segred[seg * 64 + c] = m;
  }
  __syncthreads();

  // final combine: wave wv owns rows wv*32..+31, lane = col c (0..63)
  {
    int c  = lane;
    int r0 = wv * 32;
    int b  = mb >> 4;
    int gcol = nb * 64 + c;
    float g = ctx[b * 512 + gcol] + segred[(r0 >> 6) * 64 + c];
    int lbase = (64 + c) * LDP;
    int obase = (128 + c) * LDP;
    float lw0 = bf1(Xt[lbase + max(r0 - 2, 0)]);
    float lw1 = bf1(Xt[lbase + max(r0 - 1, 0)]);
    float lw2 = bf1(Xt[lbase + r0]);
    float lw3 = bf1(Xt[lbase + r0 + 1]);
    size_t obase_g = ((size_t)(mb * 256 + r0)) * 512 + gcol;
#pragma unroll
    for (int j = 0; j < 32; j++) {
      int rn = min(r0 + j + 2, 255);
      float lw4 = bf1(Xt[lbase + rn]);
      float lm = fmaxf(fmaxf(fmaxf(lw0, lw1), fmaxf(lw2, lw3)), lw4);
      float o = bf1(Xt[obase + r0 + j]);
      out[obase_g + (size_t)j * 512] = g * o + lm;
      lw0 = lw1; lw1 = lw2; lw2 = lw3; lw3 = lw4;
    }
  }

  // side buffers for tile-boundary loc-window fixup (rows 0,1,254,255)
  if (tid < 256) {
    int rsel = tid >> 6, c = tid & 63;
    int r = (rsel < 2) ? rsel : (252 + rsel);   // 0,1,254,255
    int b = mb >> 4;
    float g = ctx[b * 512 + nb * 64 + c] + segred[(r >> 6) * 64 + c];
    float o = bf1(Xt[(128 + c) * LDP + r]);
    int gr = mb * 4 + rsel;
    sideLoc[gr * 512 + nb * 64 + c] = Xt[(64 + c) * LDP + r];
    sideGO[gr * 512 + nb * 64 + c]  = g * o;
  }
}

// ---------- K8: fixup for loc windows crossing 256-row tile boundaries ----------
__global__ void fixup_kernel(const unsigned short* __restrict__ sideLoc,
                             const float* __restrict__ sideGO,
                             float* __restrict__ out) {
  int rb = blockIdx.x;      // 0..63
  int tb = rb & 15;         // tile index within b
  int t = threadIdx.x;      // 256
  int rsel = t >> 6, cq = t & 63;
#pragma unroll
  for (int k = 0; k < 8; k++) {
    int c = cq * 8 + k;
    float miss;
    int rl;
    if (rsel == 0) {
      if (tb == 0) continue;
      miss = fmaxf(bf1(sideLoc[((rb - 1) * 4 + 2) * 512 + c]),
                   bf1(sideLoc[((rb - 1) * 4 + 3) * 512 + c]));
      rl = 0;
    } else if (rsel == 1) {
      if (tb == 0) continue;
      miss = bf1(sideLoc[((rb - 1) * 4 + 3) * 512 + c]);
      rl = 1;
    } else if (rsel == 2) {
      if (tb == 15) continue;
      miss = bf1(sideLoc[((rb + 1) * 4 + 0) * 512 + c]);
      rl = 254;
    } else {
      if (tb == 15) continue;
      miss = fmaxf(bf1(sideLoc[((rb + 1) * 4 + 0) * 512 + c]),
                   bf1(sideLoc[((rb + 1) * 4 + 1) * 512 + c]));
      rl = 255;
    }
    size_t oi = ((size_t)rb * 256 + rl) * 512 + c;
    float cand = sideGO[(rb * 4 + rsel) * 512 + c] + miss;
    out[oi] = fmaxf(out[oi], cand);
  }
}

// ---------- launch ----------
extern "C" void kernel_launch(void* const* d_in, const int* in_sizes, int n_in,
                              void* d_out, int out_size, void* d_ws, size_t ws_size,
                              hipStream_t stream) {
  const float* inp  = (const float*)d_in[0];
  const float* W    = (const float*)d_in[1];
  const float* bias = (const float*)d_in[2];
  float* out = (float*)d_out;
  char* ws = (char*)d_ws;

  const size_t INP_OFF  = 0;                   // bf16 inp: 33,554,432
  const size_t W_OFF    = 33554432;            // bf16 W[1536:3072]: 3,145,728
  const size_t MU_OFF   = 36700160;            // f32 mu: 16,384
  const size_t U_OFF    = MU_OFF + 16384;      // f32 u: 16,384
  const size_t V_OFF    = U_OFF + 16384;       // f32 v: 16,384
  const size_t AGG_OFF  = V_OFF + 16384;       // f32 agg: 8,192
  const size_t CTX_OFF  = AGG_OFF + 8192;      // f32 ctx: 8,192
  const size_t SL_OFF   = CTX_OFF + 8192;      // sideLoc bf16: 262,144
  const size_t SG_OFF   = SL_OFF + 262144;     // sideGO f32: 524,288
  const size_t UP_OFF   = SG_OFF + 524288;     // f32 uP: 256*1024*4 = 1,048,576
  const size_t ML_OFF   = UP_OFF + 1048576;    // f32 mlzl: 2,048

  unsigned short* inp_bf = (unsigned short*)(ws + INP_OFF);
  unsigned short* w_bf   = (unsigned short*)(ws + W_OFF);
  float* mu     = (float*)(ws + MU_OFF);
  float* u      = (float*)(ws + U_OFF);
  float* v      = (float*)(ws + V_OFF);
  float* agg    = (float*)(ws + AGG_OFF);
  float* ctx    = (float*)(ws + CTX_OFF);
  unsigned short* sideLoc = (unsigned short*)(ws + SL_OFF);
  float* sideGO = (float*)(ws + SG_OFF);
  float* uP     = (float*)(ws + UP_OFF);
  float* mlzl   = (float*)(ws + ML_OFF);

  hipFuncSetAttribute(reinterpret_cast<const void*>(gemm_fused),
                      hipFuncAttributeMaxDynamicSharedMemorySize, 114688);

  hipMemsetAsync(ws + MU_OFF, 0, 3 * 16384, stream);  // zero mu, u, v
  convert_mean_kernel<<<512, 256, 0, stream>>>(inp, W, inp_bf, w_bf, mu);
  agg_kernel<<<512, 256, 0, stream>>>(mu, W, bias, agg);
  v_kernel<<<dim3(4, 8), 256, 0, stream>>>(agg, W, v);
  scores_u_kernel<<<256, 256, 0, stream>>>(inp_bf, v, uP, mlzl);
  ufin_kernel<<<16, 256, 0, stream>>>(uP, mlzl, u);
  ctx_kernel<<<512, 256, 0, stream>>>(u, W, bias, ctx);
  gemm_fused<<<512, 512, 114688, stream>>>((const __hip_bfloat16*)inp_bf,
                                           (const __hip_bfloat16*)w_bf,
                                           bias + 3 * A_, ctx, out, sideLoc, sideGO);
  fixup_kernel<<<64, 256, 0, stream>>>(sideLoc, sideGO, out);
}